// Round 21
// baseline (28.468 us; speedup 1.0000x reference)
//
#include <hip/hip_runtime.h>
#include <math.h>

typedef __fp16 h2 __attribute__((ext_vector_type(2)));
typedef float  f4 __attribute__((ext_vector_type(4)));   // native vec for nt-store

#define H_IN   136
#define W_IN   200
#define HWP    (H_IN * W_IN)       // 27200
#define OH     272
#define OW     400
#define RB     17                  // 8 strips of 17 rows
#define NSTRIP 8
#define LROWS  (RB + 1)            // 18 = 9 row-pairs
#define CH     8
#define CIN    8
#define NPARAM 169
#define NEG_LOG2E (-1.4426950408889634f)

// R21 = R19's levers (hoisted feature loads, nt stores, fp16 MLP) stacked
// with R17's work-cuts (16-px phase-1 units sharing the 169-weight ds_read
// stream across 2 rows; RB=17 -> halo 12.5%->5.9%, grid 1024).
// Per-pixel math identical -> absmax canary 0.00390625.
// Spill canary: dur > 28us or FETCH >> 20MB -> revert to R19.

__device__ __forceinline__ h2 pkrtz(float a, float b) {
    return __builtin_amdgcn_cvt_pkrtz(a, b);
}

__device__ __forceinline__ void nt_store4(float* p, float4 v) {
    f4 nv = {v.x, v.y, v.z, v.w};
    __builtin_nontemporal_store(nv, (f4*)p);
}

__global__ __launch_bounds__(256, 3) void mask_head_fused(
    const float* __restrict__ mask_feats,   // (N, 8, H, W)
    const float* __restrict__ params,       // (n_inst, 169)
    const float* __restrict__ locations,    // (n_inst, 2)
    const int*   __restrict__ im_inds,      // (n_inst,)
    const int*   __restrict__ fpn_levels,   // (n_inst,)
    const float* __restrict__ soi_tab,      // (5,)
    float* __restrict__ out)                // (n_inst, 272, 400)
{
    __shared__ h2    sW[NPARAM];            // packed (dup) fp16 weights
    __shared__ float T[LROWS][W_IN];        // t = -log2e * logit, rows r0-1..r0+16

    const int inst = blockIdx.y;
    const int r0   = blockIdx.x * RB;
    const int tid  = threadIdx.x;

    const float* F = mask_feats + (size_t)im_inds[inst] * (CIN * HWP);

    // ---- hoisted feature loads for BOTH rows of this thread's 16-px unit ----
    const int  q_u = tid / 25;                  // row-pair 0..8
    const int  c_u = (tid - q_u * 25) * 8;
    const int  rA  = min(max(r0 - 1 + 2 * q_u, 0), H_IN - 1);   // T slot 2q
    const int  rB  = min(r0 + 2 * q_u, H_IN - 1);               // T slot 2q+1
    const bool p1  = (tid < 9 * 25);

    float4 fA0[CIN], fA1[CIN], fB0[CIN], fB1[CIN];
    if (p1) {
        #pragma unroll
        for (int ch = 0; ch < CIN; ++ch) {
            const float* qa = F + ch * HWP + rA * W_IN + c_u;
            const float* qb = F + ch * HWP + rB * W_IN + c_u;
            fA0[ch] = *(const float4*)qa;
            fA1[ch] = *(const float4*)(qa + 4);
            fB0[ch] = *(const float4*)qb;
            fB1[ch] = *(const float4*)(qb + 4);
        }
    }

    // ---- weight staging overlaps in-flight loads ----
    const float* P = params + inst * NPARAM;
    if (tid < NPARAM) {
        float w = P[tid];
        if ((tid >= 144 && tid < 152) || tid == 168) w *= NEG_LOG2E;
        const __fp16 hw = (__fp16)w;
        h2 v; v.x = hw; v.y = hw;
        sW[tid] = v;
    }

    const float loc_x   = locations[2 * inst];
    const float loc_y   = locations[2 * inst + 1];
    const float inv_soi = 1.0f / soi_tab[fpn_levels[inst]];
    float* O = out + (size_t)inst * (OH * OW);
    __syncthreads();

    // ---- Phase 1: 225 units of 16 px (9 row-pairs x 25 col-groups) ----
    if (p1) {
        h2 fA[CIN][4], fB[CIN][4];
        #pragma unroll
        for (int ch = 0; ch < CIN; ++ch) {
            fA[ch][0] = pkrtz(fA0[ch].x, fA0[ch].y); fA[ch][1] = pkrtz(fA0[ch].z, fA0[ch].w);
            fA[ch][2] = pkrtz(fA1[ch].x, fA1[ch].y); fA[ch][3] = pkrtz(fA1[ch].z, fA1[ch].w);
            fB[ch][0] = pkrtz(fB0[ch].x, fB0[ch].y); fB[ch][1] = pkrtz(fB0[ch].z, fB0[ch].w);
            fB[ch][2] = pkrtz(fB1[ch].x, fB1[ch].y); fB[ch][3] = pkrtz(fB1[ch].z, fB1[ch].w);
        }

        const float dx  = -8.0f * inv_soi;
        const float rx0 = (loc_x - (float)(c_u * 8 + 4)) * inv_soi;
        h2 rxh[4];
        #pragma unroll
        for (int s = 0; s < 4; ++s)
            rxh[s] = pkrtz(rx0 + (float)(2 * s) * dx, rx0 + (float)(2 * s + 1) * dx);
        const float ryAf = (loc_y - (float)(rA * 8 + 4)) * inv_soi;
        const float ryBf = (loc_y - (float)(rB * 8 + 4)) * inv_soi;
        const h2 ryA = pkrtz(ryAf, ryAf);
        const h2 ryB = pkrtz(ryBf, ryBf);
        const h2 z2  = {(__fp16)0.0f, (__fp16)0.0f};

        // layer 0 (weights read once, applied to both rows)
        h2 h0A[CH][4], h0B[CH][4];
        #pragma unroll
        for (int o = 0; o < CH; ++o) {
            const h2 b0 = sW[152 + o];
            const h2 wy = sW[o * 10 + 1];
            const h2 wx = sW[o * 10];
            const h2 baseA = __builtin_elementwise_fma(wy, ryA, b0);
            const h2 baseB = __builtin_elementwise_fma(wy, ryB, b0);
            h2 aA[4], aB[4];
            #pragma unroll
            for (int s = 0; s < 4; ++s) {
                aA[s] = __builtin_elementwise_fma(wx, rxh[s], baseA);
                aB[s] = __builtin_elementwise_fma(wx, rxh[s], baseB);
            }
            #pragma unroll
            for (int i = 0; i < CIN; ++i) {
                const h2 w = sW[o * 10 + 2 + i];
                #pragma unroll
                for (int s = 0; s < 4; ++s) {
                    aA[s] = __builtin_elementwise_fma(w, fA[i][s], aA[s]);
                    aB[s] = __builtin_elementwise_fma(w, fB[i][s], aB[s]);
                }
            }
            #pragma unroll
            for (int s = 0; s < 4; ++s) {
                h0A[o][s] = __builtin_elementwise_max(aA[s], z2);
                h0B[o][s] = __builtin_elementwise_max(aB[s], z2);
            }
        }

        // layer 1
        h2 h1A[CH][4], h1B[CH][4];
        #pragma unroll
        for (int o = 0; o < CH; ++o) {
            const h2 b = sW[160 + o];
            h2 aA[4] = {b, b, b, b};
            h2 aB[4] = {b, b, b, b};
            #pragma unroll
            for (int i = 0; i < CH; ++i) {
                const h2 w = sW[80 + o * CH + i];
                #pragma unroll
                for (int s = 0; s < 4; ++s) {
                    aA[s] = __builtin_elementwise_fma(w, h0A[i][s], aA[s]);
                    aB[s] = __builtin_elementwise_fma(w, h0B[i][s], aB[s]);
                }
            }
            #pragma unroll
            for (int s = 0; s < 4; ++s) {
                h1A[o][s] = __builtin_elementwise_max(aA[s], z2);
                h1B[o][s] = __builtin_elementwise_max(aB[s], z2);
            }
        }

        // layer 2 (pre-scaled by -log2e)
        const h2 b2 = sW[168];
        h2 tA[4] = {b2, b2, b2, b2};
        h2 tB[4] = {b2, b2, b2, b2};
        #pragma unroll
        for (int i = 0; i < CH; ++i) {
            const h2 w = sW[144 + i];
            #pragma unroll
            for (int s = 0; s < 4; ++s) {
                tA[s] = __builtin_elementwise_fma(w, h1A[i][s], tA[s]);
                tB[s] = __builtin_elementwise_fma(w, h1B[i][s], tB[s]);
            }
        }

        *(float4*)&T[2 * q_u][c_u]     = make_float4((float)tA[0].x, (float)tA[0].y,
                                                     (float)tA[1].x, (float)tA[1].y);
        *(float4*)&T[2 * q_u][c_u + 4] = make_float4((float)tA[2].x, (float)tA[2].y,
                                                     (float)tA[3].x, (float)tA[3].y);
        *(float4*)&T[2 * q_u + 1][c_u]     = make_float4((float)tB[0].x, (float)tB[0].y,
                                                         (float)tB[1].x, (float)tB[1].y);
        *(float4*)&T[2 * q_u + 1][c_u + 4] = make_float4((float)tB[2].x, (float)tB[2].y,
                                                         (float)tB[3].x, (float)tB[3].y);
    }
    __syncthreads();

    // ---- Phase 2: 850 units of 16 px (8 wide x 2 output rows), nt stores ----
    #pragma unroll 1
    for (int s = tid; s < RB * (W_IN / 4); s += 256) {
        const int rpl = s / (W_IN / 4);         // 0..16
        const int t   = s - rpl * (W_IN / 4);   // 0..49
        const int cm  = 4 * t;
        const int cl  = max(cm - 1, 0);

        const float4 mR = *(const float4*)&T[rpl + 1][cm];
        const float4 mQ = *(const float4*)&T[rpl][cm];
        const float  AR = T[rpl + 1][cl];       // == mR.x when t==0
        const float  AQ = T[rpl][cl];

        const float Aa = 0.5f * (AR + AQ);
        const float Ba = 0.5f * (mR.x + mQ.x);
        const float Ca = 0.5f * (mR.y + mQ.y);
        const float Da = 0.5f * (mR.z + mQ.z);
        const float Ea = 0.5f * (mR.w + mQ.w);

        float4 s0, s1, s2, s3;
        s0.x = __builtin_amdgcn_rcpf(1.0f + __builtin_amdgcn_exp2f(0.5f * (Aa + Ba)));
        s0.y = __builtin_amdgcn_rcpf(1.0f + __builtin_amdgcn_exp2f(Ba));
        s0.z = __builtin_amdgcn_rcpf(1.0f + __builtin_amdgcn_exp2f(0.5f * (Ba + Ca)));
        s0.w = __builtin_amdgcn_rcpf(1.0f + __builtin_amdgcn_exp2f(Ca));
        s1.x = __builtin_amdgcn_rcpf(1.0f + __builtin_amdgcn_exp2f(0.5f * (Ca + Da)));
        s1.y = __builtin_amdgcn_rcpf(1.0f + __builtin_amdgcn_exp2f(Da));
        s1.z = __builtin_amdgcn_rcpf(1.0f + __builtin_amdgcn_exp2f(0.5f * (Da + Ea)));
        s1.w = __builtin_amdgcn_rcpf(1.0f + __builtin_amdgcn_exp2f(Ea));

        s2.x = __builtin_amdgcn_rcpf(1.0f + __builtin_amdgcn_exp2f(0.5f * (AR + mR.x)));
        s2.y = __builtin_amdgcn_rcpf(1.0f + __builtin_amdgcn_exp2f(mR.x));
        s2.z = __builtin_amdgcn_rcpf(1.0f + __builtin_amdgcn_exp2f(0.5f * (mR.x + mR.y)));
        s2.w = __builtin_amdgcn_rcpf(1.0f + __builtin_amdgcn_exp2f(mR.y));
        s3.x = __builtin_amdgcn_rcpf(1.0f + __builtin_amdgcn_exp2f(0.5f * (mR.y + mR.z)));
        s3.y = __builtin_amdgcn_rcpf(1.0f + __builtin_amdgcn_exp2f(mR.z));
        s3.z = __builtin_amdgcn_rcpf(1.0f + __builtin_amdgcn_exp2f(0.5f * (mR.z + mR.w)));
        s3.w = __builtin_amdgcn_rcpf(1.0f + __builtin_amdgcn_exp2f(mR.w));

        float* O0 = O + (size_t)(2 * (r0 + rpl)) * OW + 8 * t;
        nt_store4(O0,          s0);
        nt_store4(O0 + 4,      s1);
        nt_store4(O0 + OW,     s2);
        nt_store4(O0 + OW + 4, s3);
    }
}

extern "C" void kernel_launch(void* const* d_in, const int* in_sizes, int n_in,
                              void* d_out, int out_size, void* d_ws, size_t ws_size,
                              hipStream_t stream) {
    const float* mask_feats = (const float*)d_in[0];
    const float* params     = (const float*)d_in[1];
    const float* locations  = (const float*)d_in[2];
    const int*   im_inds    = (const int*)d_in[3];
    const int*   fpn_levels = (const int*)d_in[4];
    const float* soi_tab    = (const float*)d_in[5];

    const int n_inst = in_sizes[1] / NPARAM;   // 128
    dim3 grid(NSTRIP, n_inst);                 // (8, 128)
    mask_head_fused<<<grid, 256, 0, stream>>>(
        mask_feats, params, locations, im_inds, fpn_levels, soi_tab, (float*)d_out);
}

// Round 22
// 24.139 us; speedup vs baseline: 1.1793x; 1.1793x over previous
//
#include <hip/hip_runtime.h>
#include <math.h>

typedef __fp16 h2 __attribute__((ext_vector_type(2)));
typedef float  f4 __attribute__((ext_vector_type(4)));   // native vec for nt-store

#define H_IN   136
#define W_IN   200
#define HWP    (H_IN * W_IN)       // 27200
#define OH     272
#define OW     400
#define RB     8                   // low-res rows per strip (17 strips)
#define NSTRIP 17
#define LROWS  (RB + 1)            // +1 halo row above
#define CH     8
#define CIN    8
#define NPARAM 169
#define NEG_LOG2E (-1.4426950408889634f)

// R22 = revert to R19 verbatim (best verified: 24.36us). R21's stack of
// 16-px units + dual-row hoisted loads was register-toxic (64 live float4
// pre-MLP) -> 28.5us. Lesson recorded: on this kernel every lever that
// raises per-thread register footprint cancels its win (R9/R10/R14/R21).
// R19's levers: fp16 MLP (v_pk_fma_f16), feature loads hoisted above the
// weight-staging barrier, nontemporal stores for the write-once output.
// absmax canary 0.00390625.

__device__ __forceinline__ h2 pkrtz(float a, float b) {
    return __builtin_amdgcn_cvt_pkrtz(a, b);
}

__device__ __forceinline__ void nt_store4(float* p, float4 v) {
    f4 nv = {v.x, v.y, v.z, v.w};
    __builtin_nontemporal_store(nv, (f4*)p);
}

__global__ __launch_bounds__(256, 3) void mask_head_fused(
    const float* __restrict__ mask_feats,   // (N, 8, H, W)
    const float* __restrict__ params,       // (n_inst, 169)
    const float* __restrict__ locations,    // (n_inst, 2)
    const int*   __restrict__ im_inds,      // (n_inst,)
    const int*   __restrict__ fpn_levels,   // (n_inst,)
    const float* __restrict__ soi_tab,      // (5,)
    float* __restrict__ out)                // (n_inst, 272, 400)
{
    __shared__ h2    sW[NPARAM];            // packed (dup) fp16 weights
    __shared__ float T[LROWS][W_IN];        // t = -log2e * logit

    const int inst = blockIdx.y;
    const int r0   = blockIdx.x * RB;
    const int tid  = threadIdx.x;

    const float* F = mask_feats + (size_t)im_inds[inst] * (CIN * HWP);

    // ---- feature loads issued FIRST (depend only on tid/blockIdx) ----
    const int  k_u = tid / 25;
    const int  c_u = (tid - k_u * 25) * 8;
    const int  r_u = min(max(r0 - 1 + k_u, 0), H_IN - 1);
    const bool p1  = (tid < LROWS * 25);

    float4 fA[CIN], fB[CIN];
    if (p1) {
        #pragma unroll
        for (int ch = 0; ch < CIN; ++ch) {
            const float* q = F + ch * HWP + r_u * W_IN + c_u;
            fA[ch] = *(const float4*)q;
            fB[ch] = *(const float4*)(q + 4);
        }
    }

    // ---- weight staging overlaps the in-flight loads ----
    const float* P = params + inst * NPARAM;
    if (tid < NPARAM) {
        float w = P[tid];
        if ((tid >= 144 && tid < 152) || tid == 168) w *= NEG_LOG2E;
        const __fp16 hw = (__fp16)w;
        h2 v; v.x = hw; v.y = hw;
        sW[tid] = v;
    }

    const float loc_x   = locations[2 * inst];
    const float loc_y   = locations[2 * inst + 1];
    const float inv_soi = 1.0f / soi_tab[fpn_levels[inst]];
    float* O = out + (size_t)inst * (OH * OW);
    __syncthreads();

    // ---- Phase 1: 225 units of 8 px (4 half2 slots), packed fp16 MLP ----
    if (p1) {
        h2 f[CIN][4];
        #pragma unroll
        for (int ch = 0; ch < CIN; ++ch) {
            f[ch][0] = pkrtz(fA[ch].x, fA[ch].y); f[ch][1] = pkrtz(fA[ch].z, fA[ch].w);
            f[ch][2] = pkrtz(fB[ch].x, fB[ch].y); f[ch][3] = pkrtz(fB[ch].z, fB[ch].w);
        }

        const float ry  = (loc_y - (float)(r_u * 8 + 4)) * inv_soi;
        const float dx  = -8.0f * inv_soi;
        const float rx0 = (loc_x - (float)(c_u * 8 + 4)) * inv_soi;
        h2 rxh[4];
        #pragma unroll
        for (int s = 0; s < 4; ++s)
            rxh[s] = pkrtz(rx0 + (float)(2 * s) * dx, rx0 + (float)(2 * s + 1) * dx);
        const h2 ryh = pkrtz(ry, ry);
        const h2 z2  = {(__fp16)0.0f, (__fp16)0.0f};

        h2 h0[CH][4];
        #pragma unroll
        for (int o = 0; o < CH; ++o) {
            const h2 base = __builtin_elementwise_fma(sW[o * 10 + 1], ryh, sW[152 + o]);
            const h2 wx = sW[o * 10];
            h2 a[4];
            #pragma unroll
            for (int s = 0; s < 4; ++s) a[s] = __builtin_elementwise_fma(wx, rxh[s], base);
            #pragma unroll
            for (int i = 0; i < CIN; ++i) {
                const h2 w = sW[o * 10 + 2 + i];
                #pragma unroll
                for (int s = 0; s < 4; ++s) a[s] = __builtin_elementwise_fma(w, f[i][s], a[s]);
            }
            #pragma unroll
            for (int s = 0; s < 4; ++s) h0[o][s] = __builtin_elementwise_max(a[s], z2);
        }

        h2 h1[CH][4];
        #pragma unroll
        for (int o = 0; o < CH; ++o) {
            const h2 b = sW[160 + o];
            h2 a[4] = {b, b, b, b};
            #pragma unroll
            for (int i = 0; i < CH; ++i) {
                const h2 w = sW[80 + o * CH + i];
                #pragma unroll
                for (int s = 0; s < 4; ++s) a[s] = __builtin_elementwise_fma(w, h0[i][s], a[s]);
            }
            #pragma unroll
            for (int s = 0; s < 4; ++s) h1[o][s] = __builtin_elementwise_max(a[s], z2);
        }

        const h2 b2 = sW[168];
        h2 t[4] = {b2, b2, b2, b2};
        #pragma unroll
        for (int i = 0; i < CH; ++i) {
            const h2 w = sW[144 + i];
            #pragma unroll
            for (int s = 0; s < 4; ++s) t[s] = __builtin_elementwise_fma(w, h1[i][s], t[s]);
        }

        *(float4*)&T[k_u][c_u] = make_float4((float)t[0].x, (float)t[0].y,
                                             (float)t[1].x, (float)t[1].y);
        *(float4*)&T[k_u][c_u + 4] = make_float4((float)t[2].x, (float)t[2].y,
                                                 (float)t[3].x, (float)t[3].y);
    }
    __syncthreads();

    // ---- Phase 2: 400 units of 16 px (8 wide x 2 output rows), nt stores ----
    #pragma unroll
    for (int it = 0; it < 2; ++it) {
        const int s = tid + 256 * it;
        if (s < RB * (W_IN / 4)) {
            const int rpl = s / (W_IN / 4);         // 0..7
            const int t   = s - rpl * (W_IN / 4);   // 0..49
            const int cm  = 4 * t;
            const int cl  = max(cm - 1, 0);

            const float4 mR = *(const float4*)&T[rpl + 1][cm];
            const float4 mQ = *(const float4*)&T[rpl][cm];
            const float  AR = T[rpl + 1][cl];       // == mR.x when t==0
            const float  AQ = T[rpl][cl];

            const float Aa = 0.5f * (AR + AQ);
            const float Ba = 0.5f * (mR.x + mQ.x);
            const float Ca = 0.5f * (mR.y + mQ.y);
            const float Da = 0.5f * (mR.z + mQ.z);
            const float Ea = 0.5f * (mR.w + mQ.w);

            float4 s0, s1, s2, s3;
            s0.x = __builtin_amdgcn_rcpf(1.0f + __builtin_amdgcn_exp2f(0.5f * (Aa + Ba)));
            s0.y = __builtin_amdgcn_rcpf(1.0f + __builtin_amdgcn_exp2f(Ba));
            s0.z = __builtin_amdgcn_rcpf(1.0f + __builtin_amdgcn_exp2f(0.5f * (Ba + Ca)));
            s0.w = __builtin_amdgcn_rcpf(1.0f + __builtin_amdgcn_exp2f(Ca));
            s1.x = __builtin_amdgcn_rcpf(1.0f + __builtin_amdgcn_exp2f(0.5f * (Ca + Da)));
            s1.y = __builtin_amdgcn_rcpf(1.0f + __builtin_amdgcn_exp2f(Da));
            s1.z = __builtin_amdgcn_rcpf(1.0f + __builtin_amdgcn_exp2f(0.5f * (Da + Ea)));
            s1.w = __builtin_amdgcn_rcpf(1.0f + __builtin_amdgcn_exp2f(Ea));

            s2.x = __builtin_amdgcn_rcpf(1.0f + __builtin_amdgcn_exp2f(0.5f * (AR + mR.x)));
            s2.y = __builtin_amdgcn_rcpf(1.0f + __builtin_amdgcn_exp2f(mR.x));
            s2.z = __builtin_amdgcn_rcpf(1.0f + __builtin_amdgcn_exp2f(0.5f * (mR.x + mR.y)));
            s2.w = __builtin_amdgcn_rcpf(1.0f + __builtin_amdgcn_exp2f(mR.y));
            s3.x = __builtin_amdgcn_rcpf(1.0f + __builtin_amdgcn_exp2f(0.5f * (mR.y + mR.z)));
            s3.y = __builtin_amdgcn_rcpf(1.0f + __builtin_amdgcn_exp2f(mR.z));
            s3.z = __builtin_amdgcn_rcpf(1.0f + __builtin_amdgcn_exp2f(0.5f * (mR.z + mR.w)));
            s3.w = __builtin_amdgcn_rcpf(1.0f + __builtin_amdgcn_exp2f(mR.w));

            float* O0 = O + (size_t)(2 * (r0 + rpl)) * OW + 8 * t;
            nt_store4(O0,          s0);
            nt_store4(O0 + 4,      s1);
            nt_store4(O0 + OW,     s2);
            nt_store4(O0 + OW + 4, s3);
        }
    }
}

extern "C" void kernel_launch(void* const* d_in, const int* in_sizes, int n_in,
                              void* d_out, int out_size, void* d_ws, size_t ws_size,
                              hipStream_t stream) {
    const float* mask_feats = (const float*)d_in[0];
    const float* params     = (const float*)d_in[1];
    const float* locations  = (const float*)d_in[2];
    const int*   im_inds    = (const int*)d_in[3];
    const int*   fpn_levels = (const int*)d_in[4];
    const float* soi_tab    = (const float*)d_in[5];

    const int n_inst = in_sizes[1] / NPARAM;   // 128
    dim3 grid(NSTRIP, n_inst);                 // (17, 128)
    mask_head_fused<<<grid, 256, 0, stream>>>(
        mask_feats, params, locations, im_inds, fpn_levels, soi_tab, (float*)d_out);
}